// Round 15
// baseline (1232.150 us; speedup 1.0000x reference)
//
#include <hip/hip_runtime.h>
#include <stdint.h>

#define H_   16
#define DK_  128
#define DV_  128
#define HID_ 2048
#define KS_  4
#define B_   4
#define T_   2048
#define BT_  (B_*T_)     // 8192
#define QKVC (3*HID_)    // 6144
#define C_   32          // scan chunk length
#define RS_  32          // state rows per block
#define NC_  (T_/C_)     // 64 chunks

typedef unsigned short u16;
typedef short  bf16x8 __attribute__((ext_vector_type(8)));
typedef u16    u16x8  __attribute__((ext_vector_type(8)));
typedef u16    u16x4  __attribute__((ext_vector_type(4)));
typedef float  f32x4  __attribute__((ext_vector_type(4)));

__device__ __forceinline__ float b2f(u16 u){
  union { unsigned int i; float f; } v; v.i = ((unsigned int)u) << 16; return v.f;
}
__device__ __forceinline__ u16 f2b(float f){
  unsigned int x = __float_as_uint(f);
  unsigned int r = (x + 0x7FFFu + ((x >> 16) & 1u)) >> 16;
  return (u16)r;
}
__device__ __forceinline__ float sigm(float x){ return 1.0f / (1.0f + __expf(-x)); }

#define MFMA16(a,b,c) __builtin_amdgcn_mfma_f32_16x16x32_bf16((a),(b),(c),0,0,0)

// ---------------- x conversion: f32 (bf16-valued) -> bf16, vectorized ----------------
__global__ __launch_bounds__(256) void cvt_x_k(const f32x4* __restrict__ src,
                                               u16x4* __restrict__ dst, int n4)
{
  int i0 = blockIdx.x * 256 + threadIdx.x;
  int stride = gridDim.x * 256;
  for (int i = i0; i < n4; i += stride) {
    f32x4 v = src[i];
    u16x4 r; r[0] = f2b(v[0]); r[1] = f2b(v[1]); r[2] = f2b(v[2]); r[3] = f2b(v[3]);
    dst[i] = r;
  }
}

// ---------------- small-tensor conversions ----------------
__global__ __launch_bounds__(256) void cvt_small_k(
    const float* __restrict__ qcw, const float* __restrict__ kcw, const float* __restrict__ vcw,
    const float* __restrict__ qcb, const float* __restrict__ kcb, const float* __restrict__ vcb,
    const float* __restrict__ ba,  const float* __restrict__ bb,
    const float* __restrict__ lnw, const float* __restrict__ lnb,
    u16* __restrict__ canon)
{
  int i = blockIdx.x * 256 + threadIdx.x;
  if (i >= 31008) return;
  float v;
  if (i < 24576) {
    const float* s = (i < 8192) ? qcw : (i < 16384) ? kcw : vcw;
    v = s[i & 8191];
  } else if (i < 30720) {
    int j = i - 24576;
    const float* s = (j < 2048) ? qcb : (j < 4096) ? kcb : vcb;
    v = s[j & 2047];
  } else if (i < 30752) {
    int j = i - 30720;
    v = (j < 16) ? ba[j] : bb[j - 16];
  } else {
    int j = i - 30752;
    v = (j < 128) ? lnw[j] : lnb[j - 128];
  }
  canon[i] = f2b(v);
}

// ---------------- batched transpose ----------------
__global__ __launch_bounds__(256) void transpose_b(const float* __restrict__ s0,
                                                   const float* __restrict__ s1,
                                                   const float* __restrict__ s2,
                                                   u16* __restrict__ dst,
                                                   int R, int C)
{
  int z = blockIdx.z;
  const float* src = (z == 0) ? s0 : (z == 1) ? s1 : s2;
  u16* d = dst + (size_t)z * R * C;
  __shared__ u16 t[32][33];
  int bx = blockIdx.x * 32;
  int by = blockIdx.y * 32;
  int lx = threadIdx.x & 31, ly = threadIdx.x >> 5;
  #pragma unroll
  for (int i = 0; i < 4; ++i) {
    int r = by + ly + i * 8, c = bx + lx;
    if (r < R && c < C) t[ly + i * 8][lx] = f2b(src[(size_t)r * C + c]);
  }
  __syncthreads();
  #pragma unroll
  for (int i = 0; i < 4; ++i) {
    int r = bx + ly + i * 8;
    int c = by + lx;
    if (r < C && c < R) d[(size_t)r * R + c] = t[lx][ly + i * 8];
  }
}

__device__ __forceinline__ void gload_lds16(const void* gp, void* lp){
  __builtin_amdgcn_global_load_lds(
      (const __attribute__((address_space(1))) void*)gp,
      (__attribute__((address_space(3))) void*)lp, 16, 0, 0);
}

// ---------------- 256x256 double-buffered bf16 GEMM (2-phase) ----------------
// Best measured GEMM for these shapes (non-scan 819 us). Counted-vmcnt variants
// (R11 BK=32: 859, R12 BK=64/BN=128: 905) both lost.
#define GBM 256
#define GBN 256
#define GBK 64

__global__ __launch_bounds__(512, 2) void gemm256(const u16* __restrict__ A, int lda,
                                                  const u16* __restrict__ Bt, int ldb,
                                                  void* __restrict__ C, int ldc,
                                                  int K, int out_f32)
{
  __shared__ u16 lsA[2][GBM * GBK];   // 64 KB
  __shared__ u16 lsB[2][GBN * GBK];   // 64 KB
  int tid = threadIdx.x, wid = tid >> 6, lane = tid & 63;
  int l16 = lane & 15, quad = lane >> 4;
  int wr = wid >> 2, wc = wid & 3;

  int nbx = gridDim.x;
  int nwg = nbx * gridDim.y;
  int flat = blockIdx.y * nbx + blockIdx.x;
  int swzid = ((nwg & 7) == 0) ? ((flat & 7) * (nwg >> 3) + (flat >> 3)) : flat;
  int m0 = (swzid / nbx) * GBM;
  int n0 = (swzid % nbx) * GBN;

  f32x4 acc[8][4] = {};

  auto STAGE = [&](int t, int bi){
    int k0 = t * GBK;
    #pragma unroll
    for (int ld = 0; ld < 4; ++ld) {
      int slot = ld * 512 + tid;
      int row = slot >> 3, cg = slot & 7;
      int lofs = (ld * 512 + wid * 64) * 8;          // wave-uniform base (elems)
      gload_lds16(A  + (size_t)(m0 + row) * lda + k0 + cg * 8, &lsA[bi][lofs]);
      gload_lds16(Bt + (size_t)(n0 + row) * ldb + k0 + cg * 8, &lsB[bi][lofs]);
    }
  };

  STAGE(0, 0);
  __syncthreads();

  int NT = K / GBK;
  for (int t = 0; t < NT; ++t) {
    int bi = t & 1;
    if (t + 1 < NT) STAGE(t + 1, bi ^ 1);
    const u16* pA = lsA[bi];
    const u16* pB = lsB[bi];
    #pragma unroll
    for (int ks = 0; ks < 2; ++ks) {
      bf16x8 bfr[4];
      #pragma unroll
      for (int ni = 0; ni < 4; ++ni)
        bfr[ni] = *(const bf16x8*)&pB[(wc * 64 + ni * 16 + l16) * GBK + ks * 32 + quad * 8];
      #pragma unroll
      for (int mi = 0; mi < 8; ++mi) {
        bf16x8 af = *(const bf16x8*)&pA[(wr * 128 + mi * 16 + l16) * GBK + ks * 32 + quad * 8];
        #pragma unroll
        for (int ni = 0; ni < 4; ++ni)
          acc[mi][ni] = MFMA16(af, bfr[ni], acc[mi][ni]);
      }
    }
    __syncthreads();
  }

  #pragma unroll
  for (int mi = 0; mi < 8; ++mi)
    #pragma unroll
    for (int ni = 0; ni < 4; ++ni)
      #pragma unroll
      for (int r = 0; r < 4; ++r) {
        int m = m0 + wr * 128 + mi * 16 + quad * 4 + r;
        int n = n0 + wc * 64 + ni * 16 + l16;
        if (out_f32) ((float*)C)[(size_t)m * ldc + n] = acc[mi][ni][r];
        else         ((u16*)C)[(size_t)m * ldc + n] = f2b(acc[mi][ni][r]);
      }
}

// ---------------- alpha/beta ----------------
__global__ __launch_bounds__(256) void ab_k(const u16* __restrict__ x,
                                            const u16* __restrict__ WabT,
                                            const u16* __restrict__ ba,
                                            const u16* __restrict__ bb,
                                            float* __restrict__ ab)
{
  int j = threadIdx.x & 31, rl = threadIdx.x >> 5;
  int row = blockIdx.x * 8 + rl;
  const u16x8* xr = (const u16x8*)(x + (size_t)row * HID_);
  const u16x8* wr = (const u16x8*)(WabT + (size_t)j * HID_);
  float acc = 0.f;
  for (int k = 0; k < HID_ / 8; ++k) {
    u16x8 xv = xr[k], wv = wr[k];
    #pragma unroll
    for (int i = 0; i < 8; ++i) acc += b2f(xv[i]) * b2f(wv[i]);
  }
  float bias = (j < 16) ? b2f(ba[j]) : b2f(bb[j - 16]);
  float sg = sigm(acc + bias);
  if (j < 16) ab[(size_t)row * 16 + j] = sg;
  else        ab[(size_t)BT_ * 16 + (size_t)row * 16 + (j - 16)] = sg;
}

// ---------------- causal dwconv (KS=4) + silu; ALL batches in one launch ----------------
__global__ __launch_bounds__(256) void conv_silu_k(const u16* __restrict__ in,   // [BT_][QKVC]
                                                   const u16* __restrict__ cwv,
                                                   const u16* __restrict__ cbv,
                                                   u16* __restrict__ out)
{
  int idx  = blockIdx.x * 256 + threadIdx.x;
  int col8 = idx % (QKVC / 8);
  int gt   = idx / (QKVC / 8);           // global row in [0, BT_)
  int t    = gt & (T_ - 1);              // within-batch time (causality boundary)
  int col  = col8 * 8;
  int s = col >> 11;

  u16 wl[32];
  #pragma unroll
  for (int i = 0; i < 4; ++i)
    *(u16x8*)(wl + i * 8) = *(const u16x8*)(cwv + (size_t)col * KS_ + i * 8);
  u16x8 bv = *(const u16x8*)(cbv + col);

  float acc[8];
  #pragma unroll
  for (int j = 0; j < 8; ++j) acc[j] = b2f(bv[j]);

  #pragma unroll
  for (int tap = 0; tap < KS_; ++tap) {
    int tt = t - 3 + tap;
    if (tt >= 0) {
      u16x8 xv = *(const u16x8*)(in + (size_t)(gt - 3 + tap) * QKVC + col);
      #pragma unroll
      for (int j = 0; j < 8; ++j) acc[j] = fmaf(b2f(xv[j]), b2f(wl[j * 4 + tap]), acc[j]);
    }
  }
  float scale = (s == 1) ? 0.08838834764831845f : 1.0f;
  u16x8 rv;
  #pragma unroll
  for (int j = 0; j < 8; ++j) {
    float a = acc[j];
    rv[j] = f2b(a * sigm(a) * scale);
  }
  *(u16x8*)(out + (size_t)gt * QKVC + col) = rv;
}

// ---------------- chunked gated delta-rule scan (UT transform, MFMA) ----------------
// R15: merge ph2 into ph3a -> 3 barriers/chunk (was 4). Key dataflow facts:
//  * SK0's only consumer is wave0's solve -> wave0 computes all 4 SK0 tiles itself
//    (same-wave LDS ordering, no barrier).
//  * each SQ0 tile's only consumer is the wave that owns that output tile ->
//    waves 4-7 compute their own SQ0 tile.
//  * waves 1-3 take all 6 next-chunk KK/KQ jobs (2 each) during the solve.
// Cross-wave reads all remain >=1 barrier after their writes (audit in R14 + above).
// FP expressions unchanged -> absmax fingerprint 0.04443359 (race check).
__global__ __launch_bounds__(512) void chunk_scan_k(const u16* __restrict__ qkv,
                                                    const float* __restrict__ ab,
                                                    u16* __restrict__ o)
{
  __shared__ __align__(16) char smem[107648];
  float (*SK0)[33] = (float(*)[33])(smem + 94464);
  float (*SQ0)[33] = (float(*)[33])(smem + 98688);
  float (*PL4)[4]  = (float(*)[4])(smem + 102912);
  float (*U)[33]   = (float(*)[33])(smem + 103424);
  u16 (*Sh)[136]   = (u16(*)[136])(smem + 34816);
  u16 (*Sl)[136]   = (u16(*)[136])(smem + 43520);

  int bid = blockIdx.x;
  int chain = bid & 63, rblk = bid >> 6;
  int b = chain >> 4, h = chain & 15;
  int tid = threadIdx.x, wv = tid >> 6, lane = tid & 63;
  int l16 = lane & 15, quad = lane >> 4;

  const u16* kbase = qkv + (size_t)b * T_ * QKVC + HID_ + h * DK_;
  const u16* qbase = qkv + (size_t)b * T_ * QKVC + h * DK_;
  const u16* vbase = qkv + (size_t)b * T_ * QKVC + 2 * HID_ + h * DV_ + rblk * RS_;
  const float* abase = ab + (size_t)b * T_ * 16 + h;
  const float* bbase = abase + (size_t)BT_ * 16;
  u16* obase = o + (size_t)b * T_ * 2048 + h * DV_ + rblk * RS_;

  f32x4 st[2];
  #pragma unroll
  for (int rt = 0; rt < 2; ++rt)
    #pragma unroll
    for (int r = 0; r < 4; ++r) st[rt][r] = 0.f;

  int jb = tid - 64;
  u16x8 stg[3];
  float avp = 0.f;

  auto LDA = [&](int c) {
    int t0 = c * C_;
    avp = (lane < 32) ? abase[(size_t)(t0 + lane) * 16]
                      : bbase[(size_t)(t0 + lane - 32) * 16];
  };
  auto LDI = [&](int c) {
    int t0 = c * C_;
    #pragma unroll
    for (int it = 0; it < 3; ++it) {
      int j = jb + it * 448;
      if (j < 512) {
        int t = j >> 4, g = j & 15;
        stg[it] = *(const u16x8*)(kbase + (size_t)(t0 + t) * QKVC + g * 8);
      } else if (j < 1024) {
        int j2 = j - 512, t = j2 >> 4, g = j2 & 15;
        stg[it] = *(const u16x8*)(qbase + (size_t)(t0 + t) * QKVC + g * 8);
      } else if (j < 1152) {
        int j2 = j - 1024, t = j2 >> 2, rg = j2 & 3;
        stg[it] = *(const u16x8*)(vbase + (size_t)(t0 + t) * QKVC + rg * 8);
      }
    }
  };
  auto WIM = [&](int p) {
    u16 (*Kim)[136] = (u16(*)[136])(smem + p * 8704);
    u16 (*Qim)[136] = (u16(*)[136])(smem + 17408 + p * 8704);
    u16 (*KT)[40]   = (u16(*)[40])(smem + 52224 + p * 10240);
    u16 (*Vim)[32]  = (u16(*)[32])(smem + 72704 + p * 2048);
    #pragma unroll
    for (int it = 0; it < 3; ++it) {
      int j = jb + it * 448;
      if (j < 512) {
        int t = j >> 4, g = j & 15;
        *(u16x8*)&Kim[t][g * 8] = stg[it];
        int blk = ((t >> 3) ^ (g & 3)) << 3;
        int tl = t & 7;
        #pragma unroll
        for (int e = 0; e < 8; ++e)
          KT[g * 8 + e][blk + tl] = stg[it][e];
      } else if (j < 1024) {
        int j2 = j - 512, t = j2 >> 4, g = j2 & 15;
        *(u16x8*)&Qim[t][g * 8] = stg[it];
      } else if (j < 1152) {
        int j2 = j - 1024, t = j2 >> 2, rg = j2 & 3;
        *(u16x8*)&Vim[t][rg * 8] = stg[it];
      }
    }
  };
  auto dotKK = [&](const u16 (*Kim)[136], float (*KK)[36], int mt, int nt) {
    f32x4 acc = {0.f,0.f,0.f,0.f};
    #pragma unroll
    for (int ks = 0; ks < 4; ++ks) {
      bf16x8 A = *(const bf16x8*)&Kim[mt * 16 + l16][ks * 32 + quad * 8];
      bf16x8 B = *(const bf16x8*)&Kim[nt * 16 + l16][ks * 32 + quad * 8];
      acc = MFMA16(A, B, acc);
    }
    #pragma unroll
    for (int r = 0; r < 4; ++r) KK[mt * 16 + quad * 4 + r][nt * 16 + l16] = acc[r];
  };
  auto dotKQ = [&](const u16 (*Qim)[136], const u16 (*Kim)[136], float (*KQ)[33],
                   int mt, int nt) {
    f32x4 acc = {0.f,0.f,0.f,0.f};
    #pragma unroll
    for (int ks = 0; ks < 4; ++ks) {
      bf16x8 A = *(const bf16x8*)&Qim[mt * 16 + l16][ks * 32 + quad * 8];
      bf16x8 B = *(const bf16x8*)&Kim[nt * 16 + l16][ks * 32 + quad * 8];
      acc = MFMA16(A, B, acc);
    }
    #pragma unroll
    for (int r = 0; r < 4; ++r) KQ[mt * 16 + quad * 4 + r][nt * 16 + l16] = acc[r];
  };
  auto dotS = [&](const u16 (*Aarr)[136], int tt, int rr, float (*OUT)[33]) {
    f32x4 acc = {0.f,0.f,0.f,0.f};
    #pragma unroll
    for (int ks = 0; ks < 4; ++ks) {
      bf16x8 A  = *(const bf16x8*)&Aarr[tt * 16 + l16][ks * 32 + quad * 8];
      bf16x8 Bh = *(const bf16x8*)&Sh[rr * 16 + l16][ks * 32 + quad * 8];
      bf16x8 Bl = *(const bf16x8*)&Sl[rr * 16 + l16][ks * 32 + quad * 8];
      acc = MFMA16(A, Bh, acc);
      acc = MFMA16(A, Bl, acc);
    }
    #pragma unroll
    for (int r = 0; r < 4; ++r) OUT[tt * 16 + quad * 4 + r][rr * 16 + l16] = acc[r];
  };

  // ---- prologue: stage chunk 0 images, preload chunk 1 regs, score chunk 0 ----
  if (wv == 0) LDA(0);
  else { LDI(0); WIM(0); LDI(1); }
  __syncthreads();
  {
    const u16 (*Kim0)[136] = (const u16(*)[136])(smem);
    const u16 (*Qim0)[136] = (const u16(*)[136])(smem + 17408);
    float (*KK0)[36] = (float(*)[36])(smem + 76800);
    float (*KQ0)[33] = (float(*)[33])(smem + 86016);
    if (wv >= 1 && wv <= 3) {
      const int mts[3] = {0, 1, 1}, nts[3] = {0, 0, 1};
      dotKK(Kim0, KK0, mts[wv - 1], nts[wv - 1]);
    } else if (wv >= 4 && wv <= 6) {
      const int mts[3] = {0, 1, 1}, nts[3] = {0, 0, 1};
      dotKQ(Qim0, Kim0, KQ0, mts[wv - 4], nts[wv - 4]);
    }
    // visibility for iter-0 readers comes from barrier A of iter 0
  }

  for (int c = 0; c < NC_; ++c) {
    int t0 = c * C_;
    int pc = c & 1, pn = pc ^ 1;
    const u16 (*KimC)[136] = (const u16(*)[136])(smem + pc * 8704);
    const u16 (*QimC)[136] = (const u16(*)[136])(smem + 17408 + pc * 8704);
    const u16 (*KTC)[40]   = (const u16(*)[40])(smem + 52224 + pc * 10240);
    const u16 (*VimC)[32]  = (const u16(*)[32])(smem + 72704 + pc * 2048);
    const float (*KKC)[36] = (const float(*)[36])(smem + 76800 + pc * 4608);
    const float (*KQC)[33] = (const float(*)[33])(smem + 86016 + pc * 4224);
    const u16 (*KimN)[136] = (const u16(*)[136])(smem + pn * 8704);
    const u16 (*QimN)[136] = (const u16(*)[136])(smem + 17408 + pn * 8704);
    float (*KKN)[36] = (float(*)[36])(smem + 76800 + pn * 4608);
    float (*KQN)[33] = (float(*)[33])(smem + 86016 + pn * 4224);

    // ---- ph1: state image; gates(c); write chunk c+1 images; issue LDI(c+2) ----
    #pragma unroll
    for (int rt = 0; rt < 2; ++rt)
      #pragma unroll
      for (int r = 0; r < 4; ++r) {
        float s = st[rt][r];
        u16 hi = f2b(s);
        float lo = s - b2f(hi);
        int row = rt * 16 + quad * 4 + r;
        int col = wv * 16 + l16;
        Sh[row][col] = hi;
        Sl[row][col] = f2b(lo);
      }

    if (wv == 0) {
      float av = avp;
      float p = av;
      #pragma unroll
      for (int d = 1; d < 32; d <<= 1) {
        float up = __shfl_up(p, d);
        if (lane >= d && lane < 32) p *= up;
      }
      float pm1 = __shfl_up(p, 1);
      float bt = __shfl(av, lane + 32);
      if (lane < 32) {
        if (lane == 0) pm1 = 1.f;
        f32x4 g;
        g[0] = bt * pm1; g[1] = bt; g[2] = 1.0f / p; g[3] = p;
        *(f32x4*)PL4[lane] = g;
      }
      if (c + 1 < NC_) LDA(c + 1);
    } else {
      if (c + 1 < NC_) WIM(pn);
      if (c + 2 < NC_) LDI(c + 2);
    }
    __syncthreads();                                 // barrier A

    // ---- merged ph2+ph3a (3-barrier schedule) ----
    union { u16x8 u; bf16x8 b; } gh, gl;
    int omt = (wv - 4) >> 1, ont = (wv - 4) & 1;     // output tile for wv>=4
    if (wv == 0) {
      // own SK0 tiles (same-wave write->read, no barrier), then solve
      dotS(KimC, 0, 0, SK0); dotS(KimC, 0, 1, SK0);
      dotS(KimC, 1, 0, SK0); dotS(KimC, 1, 1, SK0);
      __builtin_amdgcn_s_setprio(1);
      if (lane < 32) {
        float ub[C_];
        #pragma unroll
        for (int t = 0; t < C_; ++t) {
          f32x4 g = *(const f32x4*)PL4[t];
          float u = g[0] * SK0[t][lane] - g[1] * b2f(VimC[t][lane]);
          float acc = 0.f;
          #pragma unroll
          for (int i4 = 0; i4 < t / 4; ++i4) {
            f32x4 kk = *(const f32x4*)&KKC[t][i4 * 4];   // uniform b128 broadcast
            acc = fmaf(kk[0], ub[i4 * 4 + 0], acc);
            acc = fmaf(kk[1], ub[i4 * 4 + 1], acc);
            acc = fmaf(kk[2], ub[i4 * 4 + 2], acc);
            acc = fmaf(kk[3], ub[i4 * 4 + 3], acc);
          }
          #pragma unroll
          for (int i = (t / 4) * 4; i < t; ++i)
            acc = fmaf(KKC[t][i], ub[i], acc);
          u = fmaf(-g[0], acc, u);
          U[t][lane] = u;
          ub[t] = g[2] * u;
        }
      }
      __builtin_amdgcn_s_setprio(0);
    } else if (wv <= 3) {
      if (c + 1 < NC_) {
        const int mts[3] = {0, 1, 1}, nts[3] = {0, 0, 1};
        dotKK(KimN, KKN, mts[wv - 1], nts[wv - 1]);
        dotKQ(QimN, KimN, KQN, mts[wv - 1], nts[wv - 1]);
      }
    } else {
      dotS(QimC, omt, ont, SQ0);                      // own output tile's SQ0
      int trow = omt * 16 + l16;
      float Pt = PL4[trow][3];
      #pragma unroll
      for (int e = 0; e < 8; ++e) {
        int i = quad * 8 + e;
        float gv = (i <= trow) ? (-Pt * PL4[i][2] * KQC[trow][i]) : 0.f;
        u16 h2 = f2b(gv);
        gh.u[e] = h2; gl.u[e] = f2b(gv - b2f(h2));
      }
    }
    __syncthreads();                                 // barrier B

    // ---- ph3b: all waves state update from shared U; waves 4-7 outputs ----
    {
      float PL31 = PL4[31][3];

      #pragma unroll
      for (int rt = 0; rt < 2; ++rt) {
        union { u16x8 u; bf16x8 b; } ah, al;
        #pragma unroll
        for (int e = 0; e < 8; ++e) {
          int i = quad * 8 + e;
          float uv = U[i][rt * 16 + l16];
          float ucv = -PL31 * PL4[i][2] * uv;
          u16 hh = f2b(ucv);
          ah.u[e] = hh; al.u[e] = f2b(ucv - b2f(hh));
        }
        int col = wv * 16 + l16;
        bf16x8 Bk = *(const bf16x8*)&KTC[col][(quad ^ ((col >> 3) & 3)) << 3];
        f32x4 cacc;
        #pragma unroll
        for (int r = 0; r < 4; ++r) cacc[r] = PL31 * st[rt][r];
        cacc = MFMA16(ah.b, Bk, cacc);
        cacc = MFMA16(al.b, Bk, cacc);
        st[rt] = cacc;
      }

      if (wv >= 4) {
        union { u16x8 u; bf16x8 b; } uth, utl;
        #pragma unroll
        for (int e = 0; e < 8; ++e) {
          int i = quad * 8 + e;
          float uv = U[i][ont * 16 + l16];
          u16 h1 = f2b(uv);
          uth.u[e] = h1; utl.u[e] = f2b(uv - b2f(h1));
        }
        f32x4 oacc;
        #pragma unroll
        for (int r = 0; r < 4; ++r) {
          int t = omt * 16 + quad * 4 + r;
          oacc[r] = PL4[t][3] * SQ0[t][ont * 16 + l16];
        }
        oacc = MFMA16(gh.b, uth.b, oacc);
        oacc = MFMA16(gh.b, utl.b, oacc);
        oacc = MFMA16(gl.b, uth.b, oacc);
        #pragma unroll
        for (int r = 0; r < 4; ++r) {
          int t = omt * 16 + quad * 4 + r;
          obase[(size_t)(t0 + t) * 2048 + ont * 16 + l16] = f2b(oacc[r]);
        }
      }
    }
    __syncthreads();                                 // barrier C
  }
}

// ---------------- LayerNorm(DV) * sigmoid(g) ----------------
__global__ __launch_bounds__(256) void ln_gate_k(const u16* __restrict__ o_raw,
                                                 const u16* __restrict__ g,
                                                 const u16* __restrict__ lnw,
                                                 const u16* __restrict__ lnb,
                                                 u16* __restrict__ o_ln)
{
  int gid = blockIdx.x * 4 + (threadIdx.x >> 6);
  int lane = threadIdx.x & 63;
  int row = gid >> 4, h = gid & 15;
  size_t ofs = (size_t)row * 2048 + h * 128 + lane * 2;
  unsigned int e2 = *(const unsigned int*)(o_raw + ofs);
  float ex = b2f((u16)(e2 & 0xffff)), ey = b2f((u16)(e2 >> 16));
  float s = ex + ey, ss = ex * ex + ey * ey;
  #pragma unroll
  for (int m = 1; m < 64; m <<= 1) { s += __shfl_xor(s, m); ss += __shfl_xor(ss, m); }
  float mean = s * (1.f / 128.f);
  float var  = ss * (1.f / 128.f) - mean * mean;
  float rstd = rsqrtf(fmaxf(var, 0.f) + 1e-5f);
  float w0 = b2f(lnw[lane * 2]), w1 = b2f(lnw[lane * 2 + 1]);
  float b0 = b2f(lnb[lane * 2]), b1 = b2f(lnb[lane * 2 + 1]);
  unsigned int g2 = *(const unsigned int*)(g + ofs);
  float g0 = sigm(b2f((u16)(g2 & 0xffff))), g1 = sigm(b2f((u16)(g2 >> 16)));
  float r0 = ((ex - mean) * rstd * w0 + b0) * g0;
  float r1 = ((ey - mean) * rstd * w1 + b1) * g1;
  *(unsigned int*)(o_ln + ofs) = (unsigned int)f2b(r0) | ((unsigned int)f2b(r1) << 16);
}

// ---------------- host launch ----------------
extern "C" void kernel_launch(void* const* d_in, const int* in_sizes, int n_in,
                              void* d_out, int out_size, void* d_ws, size_t ws_size,
                              hipStream_t stream)
{
  const float* x   = (const float*)d_in[0];
  const float* Wq  = (const float*)d_in[1];
  const float* Wk  = (const float*)d_in[2];
  const float* Wv  = (const float*)d_in[3];
  const float* Wa  = (const float*)d_in[4];
  const float* ba  = (const float*)d_in[5];
  const float* Wb  = (const float*)d_in[6];
  const float* bb  = (const float*)d_in[7];
  const float* Wg  = (const float*)d_in[8];
  const float* Wo  = (const float*)d_in[9];
  const float* qcw = (const float*)d_in[10];
  const float* qcb = (const float*)d_in[11];
  const float* kcw = (const float*)d_in[12];
  const float* kcb = (const float*)d_in[13];
  const float* vcw = (const float*)d_in[14];
  const float* vcb = (const float*)d_in[15];
  const float* lnw = (const float*)d_in[16];
  const float* lnb = (const float*)d_in[17];
  (void)in_sizes; (void)n_in; (void)out_size;

  char* ws = (char*)d_ws;
  size_t off = 0;
  auto alloc = [&](size_t bytes) -> void* {
    void* p = ws + off; off += (bytes + 255) & ~(size_t)255; return p;
  };
  u16* WT    = (u16*)alloc((size_t)3 * HID_ * HID_ * 2);
  u16* WabT  = (u16*)alloc((size_t)32 * HID_ * 2);
  u16* xc    = (u16*)alloc((size_t)BT_ * HID_ * 2);
  u16* canon = (u16*)alloc((size_t)31008 * 2);
  u16* post  = (u16*)alloc((size_t)BT_ * QKVC * 2);
  float* abuf = (float*)alloc((size_t)2 * BT_ * 16 * 4);
  size_t base_off = off;

  size_t fused_need = base_off + (((size_t)BT_ * QKVC * 2 + 255) & ~(size_t)255);
  int fused = (fused_need <= ws_size);
  u16* preC;
  if (fused) preC = (u16*)alloc((size_t)BT_ * QKVC * 2);
  else       preC = (u16*)alloc((size_t)BT_ * HID_ * 2 * 2);
  if (off > ws_size) return;

  u16* cw_c  = canon;
  u16* cb_c  = canon + 24576;
  u16* ba_c  = canon + 30720;
  u16* bb_c  = canon + 30736;
  u16* lnw_c = canon + 30752;
  u16* lnb_c = canon + 30880;

  u16* o_raw = preC;
  u16* g_raw = post;
  u16* o_ln  = post + (size_t)BT_ * HID_;
  u16* WTg   = WT;

  dim3 tb(256), tb5(512);

  cvt_x_k<<<dim3(4096), tb, 0, stream>>>((const f32x4*)x, (u16x4*)xc, BT_ * HID_ / 4);
  cvt_small_k<<<dim3(122), tb, 0, stream>>>(qcw, kcw, vcw, qcb, kcb, vcb, ba, bb, lnw, lnb, canon);

  transpose_b<<<dim3(64, 64, 3), tb, 0, stream>>>(Wq, Wk, Wv, WT, HID_, HID_);
  transpose_b<<<dim3(1, 64, 2), tb, 0, stream>>>(Wa, Wb, Wb, WabT, HID_, 16);

  if (fused) {
    gemm256<<<dim3(QKVC / GBN, BT_ / GBM), tb5, 0, stream>>>(xc, HID_, WT, HID_, preC, QKVC, HID_, 0);
    conv_silu_k<<<dim3(BT_ * (QKVC / 8) / 256), tb, 0, stream>>>(preC, cw_c, cb_c, post);
  } else {
    for (int b = 0; b < B_; ++b) {
      const u16* xb = xc + (size_t)b * T_ * HID_;
      gemm256<<<dim3(QKVC / GBN, T_ / GBM), tb5, 0, stream>>>(xb, HID_, WT, HID_, preC, QKVC, HID_, 0);
      conv_silu_k<<<dim3(T_ * (QKVC / 8) / 256), tb, 0, stream>>>(
          preC, cw_c, cb_c, post + (size_t)b * T_ * QKVC);
    }
  }

  transpose_b<<<dim3(64, 64, 2), tb, 0, stream>>>(Wg, Wo, Wo, WTg, HID_, HID_);

  ab_k<<<dim3(BT_ / 8), tb, 0, stream>>>(xc, WabT, ba_c, bb_c, abuf);

  // chunked scan: 256 blocks x 512 threads (pipelined, 3 barriers/chunk)
  chunk_scan_k<<<dim3(256), tb5, 0, stream>>>(post, abuf, o_raw);

  gemm256<<<dim3(HID_ / GBN, BT_ / GBM), tb5, 0, stream>>>(xc, HID_, WTg, HID_, g_raw, HID_, HID_, 0);

  ln_gate_k<<<dim3(BT_ * H_ / 4), tb, 0, stream>>>(o_raw, g_raw, lnw_c, lnb_c, o_ln);

  gemm256<<<dim3(HID_ / GBN, BT_ / GBM), tb5, 0, stream>>>(o_ln, HID_,
      WT + (size_t)HID_ * HID_, HID_, d_out, HID_, HID_, 1);
}

// Round 16
// 1212.706 us; speedup vs baseline: 1.0160x; 1.0160x over previous
//
#include <hip/hip_runtime.h>
#include <stdint.h>

#define H_   16
#define DK_  128
#define DV_  128
#define HID_ 2048
#define KS_  4
#define B_   4
#define T_   2048
#define BT_  (B_*T_)     // 8192
#define QKVC (3*HID_)    // 6144
#define C_   32          // scan chunk length
#define RS_  32          // state rows per block
#define NC_  (T_/C_)     // 64 chunks

typedef unsigned short u16;
typedef short  bf16x8 __attribute__((ext_vector_type(8)));
typedef u16    u16x8  __attribute__((ext_vector_type(8)));
typedef u16    u16x4  __attribute__((ext_vector_type(4)));
typedef float  f32x4  __attribute__((ext_vector_type(4)));

__device__ __forceinline__ float b2f(u16 u){
  union { unsigned int i; float f; } v; v.i = ((unsigned int)u) << 16; return v.f;
}
__device__ __forceinline__ u16 f2b(float f){
  unsigned int x = __float_as_uint(f);
  unsigned int r = (x + 0x7FFFu + ((x >> 16) & 1u)) >> 16;
  return (u16)r;
}
__device__ __forceinline__ float sigm(float x){ return 1.0f / (1.0f + __expf(-x)); }

#define MFMA16(a,b,c) __builtin_amdgcn_mfma_f32_16x16x32_bf16((a),(b),(c),0,0,0)

// ---------------- x conversion: f32 (bf16-valued) -> bf16, vectorized ----------------
__global__ __launch_bounds__(256) void cvt_x_k(const f32x4* __restrict__ src,
                                               u16x4* __restrict__ dst, int n4)
{
  int i0 = blockIdx.x * 256 + threadIdx.x;
  int stride = gridDim.x * 256;
  for (int i = i0; i < n4; i += stride) {
    f32x4 v = src[i];
    u16x4 r; r[0] = f2b(v[0]); r[1] = f2b(v[1]); r[2] = f2b(v[2]); r[3] = f2b(v[3]);
    dst[i] = r;
  }
}

// ---------------- small-tensor conversions ----------------
__global__ __launch_bounds__(256) void cvt_small_k(
    const float* __restrict__ qcw, const float* __restrict__ kcw, const float* __restrict__ vcw,
    const float* __restrict__ qcb, const float* __restrict__ kcb, const float* __restrict__ vcb,
    const float* __restrict__ ba,  const float* __restrict__ bb,
    const float* __restrict__ lnw, const float* __restrict__ lnb,
    u16* __restrict__ canon)
{
  int i = blockIdx.x * 256 + threadIdx.x;
  if (i >= 31008) return;
  float v;
  if (i < 24576) {
    const float* s = (i < 8192) ? qcw : (i < 16384) ? kcw : vcw;
    v = s[i & 8191];
  } else if (i < 30720) {
    int j = i - 24576;
    const float* s = (j < 2048) ? qcb : (j < 4096) ? kcb : vcb;
    v = s[j & 2047];
  } else if (i < 30752) {
    int j = i - 30720;
    v = (j < 16) ? ba[j] : bb[j - 16];
  } else {
    int j = i - 30752;
    v = (j < 128) ? lnw[j] : lnb[j - 128];
  }
  canon[i] = f2b(v);
}

// ---------------- batched transpose ----------------
__global__ __launch_bounds__(256) void transpose_b(const float* __restrict__ s0,
                                                   const float* __restrict__ s1,
                                                   const float* __restrict__ s2,
                                                   u16* __restrict__ dst,
                                                   int R, int C)
{
  int z = blockIdx.z;
  const float* src = (z == 0) ? s0 : (z == 1) ? s1 : s2;
  u16* d = dst + (size_t)z * R * C;
  __shared__ u16 t[32][33];
  int bx = blockIdx.x * 32;
  int by = blockIdx.y * 32;
  int lx = threadIdx.x & 31, ly = threadIdx.x >> 5;
  #pragma unroll
  for (int i = 0; i < 4; ++i) {
    int r = by + ly + i * 8, c = bx + lx;
    if (r < R && c < C) t[ly + i * 8][lx] = f2b(src[(size_t)r * C + c]);
  }
  __syncthreads();
  #pragma unroll
  for (int i = 0; i < 4; ++i) {
    int r = bx + ly + i * 8;
    int c = by + lx;
    if (r < C && c < R) d[(size_t)r * R + c] = t[lx][ly + i * 8];
  }
}

__device__ __forceinline__ void gload_lds16(const void* gp, void* lp){
  __builtin_amdgcn_global_load_lds(
      (const __attribute__((address_space(1))) void*)gp,
      (__attribute__((address_space(3))) void*)lp, 16, 0, 0);
}

// ---------------- 256x256 double-buffered bf16 GEMM (2-phase) ----------------
// Best measured GEMM for these shapes (non-scan 819 us). Counted-vmcnt variants
// (R11 BK=32: 859, R12 BK=64/BN=128: 905) both lost.
#define GBM 256
#define GBN 256
#define GBK 64

__global__ __launch_bounds__(512, 2) void gemm256(const u16* __restrict__ A, int lda,
                                                  const u16* __restrict__ Bt, int ldb,
                                                  void* __restrict__ C, int ldc,
                                                  int K, int out_f32)
{
  __shared__ u16 lsA[2][GBM * GBK];   // 64 KB
  __shared__ u16 lsB[2][GBN * GBK];   // 64 KB
  int tid = threadIdx.x, wid = tid >> 6, lane = tid & 63;
  int l16 = lane & 15, quad = lane >> 4;
  int wr = wid >> 2, wc = wid & 3;

  int nbx = gridDim.x;
  int nwg = nbx * gridDim.y;
  int flat = blockIdx.y * nbx + blockIdx.x;
  int swzid = ((nwg & 7) == 0) ? ((flat & 7) * (nwg >> 3) + (flat >> 3)) : flat;
  int m0 = (swzid / nbx) * GBM;
  int n0 = (swzid % nbx) * GBN;

  f32x4 acc[8][4] = {};

  auto STAGE = [&](int t, int bi){
    int k0 = t * GBK;
    #pragma unroll
    for (int ld = 0; ld < 4; ++ld) {
      int slot = ld * 512 + tid;
      int row = slot >> 3, cg = slot & 7;
      int lofs = (ld * 512 + wid * 64) * 8;          // wave-uniform base (elems)
      gload_lds16(A  + (size_t)(m0 + row) * lda + k0 + cg * 8, &lsA[bi][lofs]);
      gload_lds16(Bt + (size_t)(n0 + row) * ldb + k0 + cg * 8, &lsB[bi][lofs]);
    }
  };

  STAGE(0, 0);
  __syncthreads();

  int NT = K / GBK;
  for (int t = 0; t < NT; ++t) {
    int bi = t & 1;
    if (t + 1 < NT) STAGE(t + 1, bi ^ 1);
    const u16* pA = lsA[bi];
    const u16* pB = lsB[bi];
    #pragma unroll
    for (int ks = 0; ks < 2; ++ks) {
      bf16x8 bfr[4];
      #pragma unroll
      for (int ni = 0; ni < 4; ++ni)
        bfr[ni] = *(const bf16x8*)&pB[(wc * 64 + ni * 16 + l16) * GBK + ks * 32 + quad * 8];
      #pragma unroll
      for (int mi = 0; mi < 8; ++mi) {
        bf16x8 af = *(const bf16x8*)&pA[(wr * 128 + mi * 16 + l16) * GBK + ks * 32 + quad * 8];
        #pragma unroll
        for (int ni = 0; ni < 4; ++ni)
          acc[mi][ni] = MFMA16(af, bfr[ni], acc[mi][ni]);
      }
    }
    __syncthreads();
  }

  #pragma unroll
  for (int mi = 0; mi < 8; ++mi)
    #pragma unroll
    for (int ni = 0; ni < 4; ++ni)
      #pragma unroll
      for (int r = 0; r < 4; ++r) {
        int m = m0 + wr * 128 + mi * 16 + quad * 4 + r;
        int n = n0 + wc * 64 + ni * 16 + l16;
        if (out_f32) ((float*)C)[(size_t)m * ldc + n] = acc[mi][ni][r];
        else         ((u16*)C)[(size_t)m * ldc + n] = f2b(acc[mi][ni][r]);
      }
}

// ---------------- alpha/beta ----------------
__global__ __launch_bounds__(256) void ab_k(const u16* __restrict__ x,
                                            const u16* __restrict__ WabT,
                                            const u16* __restrict__ ba,
                                            const u16* __restrict__ bb,
                                            float* __restrict__ ab)
{
  int j = threadIdx.x & 31, rl = threadIdx.x >> 5;
  int row = blockIdx.x * 8 + rl;
  const u16x8* xr = (const u16x8*)(x + (size_t)row * HID_);
  const u16x8* wr = (const u16x8*)(WabT + (size_t)j * HID_);
  float acc = 0.f;
  for (int k = 0; k < HID_ / 8; ++k) {
    u16x8 xv = xr[k], wv = wr[k];
    #pragma unroll
    for (int i = 0; i < 8; ++i) acc += b2f(xv[i]) * b2f(wv[i]);
  }
  float bias = (j < 16) ? b2f(ba[j]) : b2f(bb[j - 16]);
  float sg = sigm(acc + bias);
  if (j < 16) ab[(size_t)row * 16 + j] = sg;
  else        ab[(size_t)BT_ * 16 + (size_t)row * 16 + (j - 16)] = sg;
}

// ---------------- causal dwconv (KS=4) + silu; ALL batches in one launch ----------------
__global__ __launch_bounds__(256) void conv_silu_k(const u16* __restrict__ in,   // [BT_][QKVC]
                                                   const u16* __restrict__ cwv,
                                                   const u16* __restrict__ cbv,
                                                   u16* __restrict__ out)
{
  int idx  = blockIdx.x * 256 + threadIdx.x;
  int col8 = idx % (QKVC / 8);
  int gt   = idx / (QKVC / 8);           // global row in [0, BT_)
  int t    = gt & (T_ - 1);              // within-batch time (causality boundary)
  int col  = col8 * 8;
  int s = col >> 11;

  u16 wl[32];
  #pragma unroll
  for (int i = 0; i < 4; ++i)
    *(u16x8*)(wl + i * 8) = *(const u16x8*)(cwv + (size_t)col * KS_ + i * 8);
  u16x8 bv = *(const u16x8*)(cbv + col);

  float acc[8];
  #pragma unroll
  for (int j = 0; j < 8; ++j) acc[j] = b2f(bv[j]);

  #pragma unroll
  for (int tap = 0; tap < KS_; ++tap) {
    int tt = t - 3 + tap;
    if (tt >= 0) {
      u16x8 xv = *(const u16x8*)(in + (size_t)(gt - 3 + tap) * QKVC + col);
      #pragma unroll
      for (int j = 0; j < 8; ++j) acc[j] = fmaf(b2f(xv[j]), b2f(wl[j * 4 + tap]), acc[j]);
    }
  }
  float scale = (s == 1) ? 0.08838834764831845f : 1.0f;
  u16x8 rv;
  #pragma unroll
  for (int j = 0; j < 8; ++j) {
    float a = acc[j];
    rv[j] = f2b(a * sigm(a) * scale);
  }
  *(u16x8*)(out + (size_t)gt * QKVC + col) = rv;
}

// ---------------- chunked gated delta-rule scan (UT transform, MFMA) ----------------
// EXACT R14 version (measured 383 us, session best). Software-pipelined chunk loop:
// chunk c+1's KK/KQ computed during chunk c's serial solve; parity double-buffers
// for {Kim,Qim,Vim,KT,KK,KQ}; 4 barriers/chunk with ph2 spread 1-job-per-wave.
// R15 lesson: merging ph2 into ph3a serialized SK0 onto wave0 (the critical wave)
// and LOST 20 us despite one fewer barrier -- never add critical-wave work to save
// a barrier. FP expressions identical -> absmax fingerprint 0.04443359.
__global__ __launch_bounds__(512) void chunk_scan_k(const u16* __restrict__ qkv,
                                                    const float* __restrict__ ab,
                                                    u16* __restrict__ o)
{
  __shared__ __align__(16) char smem[107648];
  float (*SK0)[33] = (float(*)[33])(smem + 94464);
  float (*SQ0)[33] = (float(*)[33])(smem + 98688);
  float (*PL4)[4]  = (float(*)[4])(smem + 102912);
  float (*U)[33]   = (float(*)[33])(smem + 103424);
  u16 (*Sh)[136]   = (u16(*)[136])(smem + 34816);
  u16 (*Sl)[136]   = (u16(*)[136])(smem + 43520);

  int bid = blockIdx.x;
  int chain = bid & 63, rblk = bid >> 6;
  int b = chain >> 4, h = chain & 15;
  int tid = threadIdx.x, wv = tid >> 6, lane = tid & 63;
  int l16 = lane & 15, quad = lane >> 4;

  const u16* kbase = qkv + (size_t)b * T_ * QKVC + HID_ + h * DK_;
  const u16* qbase = qkv + (size_t)b * T_ * QKVC + h * DK_;
  const u16* vbase = qkv + (size_t)b * T_ * QKVC + 2 * HID_ + h * DV_ + rblk * RS_;
  const float* abase = ab + (size_t)b * T_ * 16 + h;
  const float* bbase = abase + (size_t)BT_ * 16;
  u16* obase = o + (size_t)b * T_ * 2048 + h * DV_ + rblk * RS_;

  f32x4 st[2];
  #pragma unroll
  for (int rt = 0; rt < 2; ++rt)
    #pragma unroll
    for (int r = 0; r < 4; ++r) st[rt][r] = 0.f;

  int jb = tid - 64;
  u16x8 stg[3];
  float avp = 0.f;

  auto LDA = [&](int c) {
    int t0 = c * C_;
    avp = (lane < 32) ? abase[(size_t)(t0 + lane) * 16]
                      : bbase[(size_t)(t0 + lane - 32) * 16];
  };
  auto LDI = [&](int c) {
    int t0 = c * C_;
    #pragma unroll
    for (int it = 0; it < 3; ++it) {
      int j = jb + it * 448;
      if (j < 512) {
        int t = j >> 4, g = j & 15;
        stg[it] = *(const u16x8*)(kbase + (size_t)(t0 + t) * QKVC + g * 8);
      } else if (j < 1024) {
        int j2 = j - 512, t = j2 >> 4, g = j2 & 15;
        stg[it] = *(const u16x8*)(qbase + (size_t)(t0 + t) * QKVC + g * 8);
      } else if (j < 1152) {
        int j2 = j - 1024, t = j2 >> 2, rg = j2 & 3;
        stg[it] = *(const u16x8*)(vbase + (size_t)(t0 + t) * QKVC + rg * 8);
      }
    }
  };
  auto WIM = [&](int p) {
    u16 (*Kim)[136] = (u16(*)[136])(smem + p * 8704);
    u16 (*Qim)[136] = (u16(*)[136])(smem + 17408 + p * 8704);
    u16 (*KT)[40]   = (u16(*)[40])(smem + 52224 + p * 10240);
    u16 (*Vim)[32]  = (u16(*)[32])(smem + 72704 + p * 2048);
    #pragma unroll
    for (int it = 0; it < 3; ++it) {
      int j = jb + it * 448;
      if (j < 512) {
        int t = j >> 4, g = j & 15;
        *(u16x8*)&Kim[t][g * 8] = stg[it];
        int blk = ((t >> 3) ^ (g & 3)) << 3;
        int tl = t & 7;
        #pragma unroll
        for (int e = 0; e < 8; ++e)
          KT[g * 8 + e][blk + tl] = stg[it][e];
      } else if (j < 1024) {
        int j2 = j - 512, t = j2 >> 4, g = j2 & 15;
        *(u16x8*)&Qim[t][g * 8] = stg[it];
      } else if (j < 1152) {
        int j2 = j - 1024, t = j2 >> 2, rg = j2 & 3;
        *(u16x8*)&Vim[t][rg * 8] = stg[it];
      }
    }
  };
  auto dotKK = [&](const u16 (*Kim)[136], float (*KK)[36], int mt, int nt) {
    f32x4 acc = {0.f,0.f,0.f,0.f};
    #pragma unroll
    for (int ks = 0; ks < 4; ++ks) {
      bf16x8 A = *(const bf16x8*)&Kim[mt * 16 + l16][ks * 32 + quad * 8];
      bf16x8 B = *(const bf16x8*)&Kim[nt * 16 + l16][ks * 32 + quad * 8];
      acc = MFMA16(A, B, acc);
    }
    #pragma unroll
    for (int r = 0; r < 4; ++r) KK[mt * 16 + quad * 4 + r][nt * 16 + l16] = acc[r];
  };
  auto dotKQ = [&](const u16 (*Qim)[136], const u16 (*Kim)[136], float (*KQ)[33],
                   int mt, int nt) {
    f32x4 acc = {0.f,0.f,0.f,0.f};
    #pragma unroll
    for (int ks = 0; ks < 4; ++ks) {
      bf16x8 A = *(const bf16x8*)&Qim[mt * 16 + l16][ks * 32 + quad * 8];
      bf16x8 B = *(const bf16x8*)&Kim[nt * 16 + l16][ks * 32 + quad * 8];
      acc = MFMA16(A, B, acc);
    }
    #pragma unroll
    for (int r = 0; r < 4; ++r) KQ[mt * 16 + quad * 4 + r][nt * 16 + l16] = acc[r];
  };
  auto dotS = [&](const u16 (*Aarr)[136], int tt, int rr, float (*OUT)[33]) {
    f32x4 acc = {0.f,0.f,0.f,0.f};
    #pragma unroll
    for (int ks = 0; ks < 4; ++ks) {
      bf16x8 A  = *(const bf16x8*)&Aarr[tt * 16 + l16][ks * 32 + quad * 8];
      bf16x8 Bh = *(const bf16x8*)&Sh[rr * 16 + l16][ks * 32 + quad * 8];
      bf16x8 Bl = *(const bf16x8*)&Sl[rr * 16 + l16][ks * 32 + quad * 8];
      acc = MFMA16(A, Bh, acc);
      acc = MFMA16(A, Bl, acc);
    }
    #pragma unroll
    for (int r = 0; r < 4; ++r) OUT[tt * 16 + quad * 4 + r][rr * 16 + l16] = acc[r];
  };

  // ---- prologue: stage chunk 0 images, preload chunk 1 regs, score chunk 0 ----
  if (wv == 0) LDA(0);
  else { LDI(0); WIM(0); LDI(1); }
  __syncthreads();
  {
    const u16 (*Kim0)[136] = (const u16(*)[136])(smem);
    const u16 (*Qim0)[136] = (const u16(*)[136])(smem + 17408);
    float (*KK0)[36] = (float(*)[36])(smem + 76800);
    float (*KQ0)[33] = (float(*)[33])(smem + 86016);
    if (wv >= 1 && wv <= 3) {
      const int mts[3] = {0, 1, 1}, nts[3] = {0, 0, 1};
      dotKK(Kim0, KK0, mts[wv - 1], nts[wv - 1]);
    } else if (wv >= 4 && wv <= 6) {
      const int mts[3] = {0, 1, 1}, nts[3] = {0, 0, 1};
      dotKQ(Qim0, Kim0, KQ0, mts[wv - 4], nts[wv - 4]);
    }
    // first reads of KK0/KQ0 are in iter0 ph3a, 2 barriers away
  }

  for (int c = 0; c < NC_; ++c) {
    int t0 = c * C_;
    int pc = c & 1, pn = pc ^ 1;
    const u16 (*KimC)[136] = (const u16(*)[136])(smem + pc * 8704);
    const u16 (*QimC)[136] = (const u16(*)[136])(smem + 17408 + pc * 8704);
    const u16 (*KTC)[40]   = (const u16(*)[40])(smem + 52224 + pc * 10240);
    const u16 (*VimC)[32]  = (const u16(*)[32])(smem + 72704 + pc * 2048);
    const float (*KKC)[36] = (const float(*)[36])(smem + 76800 + pc * 4608);
    const float (*KQC)[33] = (const float(*)[33])(smem + 86016 + pc * 4224);
    const u16 (*KimN)[136] = (const u16(*)[136])(smem + pn * 8704);
    const u16 (*QimN)[136] = (const u16(*)[136])(smem + 17408 + pn * 8704);
    float (*KKN)[36] = (float(*)[36])(smem + 76800 + pn * 4608);
    float (*KQN)[33] = (float(*)[33])(smem + 86016 + pn * 4224);

    // ---- ph1: state image; gates(c); write chunk c+1 images; issue LDI(c+2) ----
    #pragma unroll
    for (int rt = 0; rt < 2; ++rt)
      #pragma unroll
      for (int r = 0; r < 4; ++r) {
        float s = st[rt][r];
        u16 hi = f2b(s);
        float lo = s - b2f(hi);
        int row = rt * 16 + quad * 4 + r;
        int col = wv * 16 + l16;
        Sh[row][col] = hi;
        Sl[row][col] = f2b(lo);
      }

    if (wv == 0) {
      float av = avp;
      float p = av;
      #pragma unroll
      for (int d = 1; d < 32; d <<= 1) {
        float up = __shfl_up(p, d);
        if (lane >= d && lane < 32) p *= up;
      }
      float pm1 = __shfl_up(p, 1);
      float bt = __shfl(av, lane + 32);
      if (lane < 32) {
        if (lane == 0) pm1 = 1.f;
        f32x4 g;
        g[0] = bt * pm1; g[1] = bt; g[2] = 1.0f / p; g[3] = p;
        *(f32x4*)PL4[lane] = g;
      }
      if (c + 1 < NC_) LDA(c + 1);
    } else {
      if (c + 1 < NC_) WIM(pn);
      if (c + 2 < NC_) LDI(c + 2);
    }
    __syncthreads();

    // ---- ph2: state-dependent scores only (SK0/SQ0, 1 job per wave) ----
    if (wv < 4) dotS(KimC, wv >> 1, wv & 1, SK0);
    else        dotS(QimC, (wv - 4) >> 1, (wv - 4) & 1, SQ0);
    __syncthreads();

    // ---- ph3a: wave0 solve(c) || waves1-6 score chunk c+1 || waves4-7 G frags ----
    union { u16x8 u; bf16x8 b; } gh, gl;
    int omt = (wv - 4) >> 1, ont = (wv - 4) & 1;     // output tile for wv>=4
    if (wv == 0) {
      __builtin_amdgcn_s_setprio(1);                 // solve is the block critical path
      if (lane < 32) {
        float ub[C_];
        #pragma unroll
        for (int t = 0; t < C_; ++t) {
          f32x4 g = *(const f32x4*)PL4[t];
          float u = g[0] * SK0[t][lane] - g[1] * b2f(VimC[t][lane]);
          float acc = 0.f;
          #pragma unroll
          for (int i4 = 0; i4 < t / 4; ++i4) {
            f32x4 kk = *(const f32x4*)&KKC[t][i4 * 4];   // uniform b128 broadcast
            acc = fmaf(kk[0], ub[i4 * 4 + 0], acc);
            acc = fmaf(kk[1], ub[i4 * 4 + 1], acc);
            acc = fmaf(kk[2], ub[i4 * 4 + 2], acc);
            acc = fmaf(kk[3], ub[i4 * 4 + 3], acc);
          }
          #pragma unroll
          for (int i = (t / 4) * 4; i < t; ++i)
            acc = fmaf(KKC[t][i], ub[i], acc);
          u = fmaf(-g[0], acc, u);
          U[t][lane] = u;
          ub[t] = g[2] * u;
        }
      }
      __builtin_amdgcn_s_setprio(0);
    } else if (wv <= 3) {
      if (c + 1 < NC_) {
        const int mts[3] = {0, 1, 1}, nts[3] = {0, 0, 1};
        dotKK(KimN, KKN, mts[wv - 1], nts[wv - 1]);
        dotKQ(QimN, KimN, KQN, mts[wv - 1], nts[wv - 1]);
      }
    } else {
      if (wv <= 6 && c + 1 < NC_) {
        // covered by waves 1-3 (they do both KK and KQ); waves 4-7 do G frags only
      }
      int trow = omt * 16 + l16;
      float Pt = PL4[trow][3];
      #pragma unroll
      for (int e = 0; e < 8; ++e) {
        int i = quad * 8 + e;
        float gv = (i <= trow) ? (-Pt * PL4[i][2] * KQC[trow][i]) : 0.f;
        u16 h2 = f2b(gv);
        gh.u[e] = h2; gl.u[e] = f2b(gv - b2f(h2));
      }
    }
    __syncthreads();

    // ---- ph3b: all waves state update from shared U; waves 4-7 outputs ----
    {
      float PL31 = PL4[31][3];

      #pragma unroll
      for (int rt = 0; rt < 2; ++rt) {
        union { u16x8 u; bf16x8 b; } ah, al;
        #pragma unroll
        for (int e = 0; e < 8; ++e) {
          int i = quad * 8 + e;
          float uv = U[i][rt * 16 + l16];
          float ucv = -PL31 * PL4[i][2] * uv;
          u16 hh = f2b(ucv);
          ah.u[e] = hh; al.u[e] = f2b(ucv - b2f(hh));
        }
        int col = wv * 16 + l16;
        bf16x8 Bk = *(const bf16x8*)&KTC[col][(quad ^ ((col >> 3) & 3)) << 3];
        f32x4 cacc;
        #pragma unroll
        for (int r = 0; r < 4; ++r) cacc[r] = PL31 * st[rt][r];
        cacc = MFMA16(ah.b, Bk, cacc);
        cacc = MFMA16(al.b, Bk, cacc);
        st[rt] = cacc;
      }

      if (wv >= 4) {
        union { u16x8 u; bf16x8 b; } uth, utl;
        #pragma unroll
        for (int e = 0; e < 8; ++e) {
          int i = quad * 8 + e;
          float uv = U[i][ont * 16 + l16];
          u16 h1 = f2b(uv);
          uth.u[e] = h1; utl.u[e] = f2b(uv - b2f(h1));
        }
        f32x4 oacc;
        #pragma unroll
        for (int r = 0; r < 4; ++r) {
          int t = omt * 16 + quad * 4 + r;
          oacc[r] = PL4[t][3] * SQ0[t][ont * 16 + l16];
        }
        oacc = MFMA16(gh.b, uth.b, oacc);
        oacc = MFMA16(gh.b, utl.b, oacc);
        oacc = MFMA16(gl.b, uth.b, oacc);
        #pragma unroll
        for (int r = 0; r < 4; ++r) {
          int t = omt * 16 + quad * 4 + r;
          obase[(size_t)(t0 + t) * 2048 + ont * 16 + l16] = f2b(oacc[r]);
        }
      }
    }
    __syncthreads();
  }
}

// ---------------- LayerNorm(DV) * sigmoid(g) ----------------
__global__ __launch_bounds__(256) void ln_gate_k(const u16* __restrict__ o_raw,
                                                 const u16* __restrict__ g,
                                                 const u16* __restrict__ lnw,
                                                 const u16* __restrict__ lnb,
                                                 u16* __restrict__ o_ln)
{
  int gid = blockIdx.x * 4 + (threadIdx.x >> 6);
  int lane = threadIdx.x & 63;
  int row = gid >> 4, h = gid & 15;
  size_t ofs = (size_t)row * 2048 + h * 128 + lane * 2;
  unsigned int e2 = *(const unsigned int*)(o_raw + ofs);
  float ex = b2f((u16)(e2 & 0xffff)), ey = b2f((u16)(e2 >> 16));
  float s = ex + ey, ss = ex * ex + ey * ey;
  #pragma unroll
  for (int m = 1; m < 64; m <<= 1) { s += __shfl_xor(s, m); ss += __shfl_xor(ss, m); }
  float mean = s * (1.f / 128.f);
  float var  = ss * (1.f / 128.f) - mean * mean;
  float rstd = rsqrtf(fmaxf(var, 0.f) + 1e-5f);
  float w0 = b2f(lnw[lane * 2]), w1 = b2f(lnw[lane * 2 + 1]);
  float b0 = b2f(lnb[lane * 2]), b1 = b2f(lnb[lane * 2 + 1]);
  unsigned int g2 = *(const unsigned int*)(g + ofs);
  float g0 = sigm(b2f((u16)(g2 & 0xffff))), g1 = sigm(b2f((u16)(g2 >> 16)));
  float r0 = ((ex - mean) * rstd * w0 + b0) * g0;
  float r1 = ((ey - mean) * rstd * w1 + b1) * g1;
  *(unsigned int*)(o_ln + ofs) = (unsigned int)f2b(r0) | ((unsigned int)f2b(r1) << 16);
}

// ---------------- host launch ----------------
extern "C" void kernel_launch(void* const* d_in, const int* in_sizes, int n_in,
                              void* d_out, int out_size, void* d_ws, size_t ws_size,
                              hipStream_t stream)
{
  const float* x   = (const float*)d_in[0];
  const float* Wq  = (const float*)d_in[1];
  const float* Wk  = (const float*)d_in[2];
  const float* Wv  = (const float*)d_in[3];
  const float* Wa  = (const float*)d_in[4];
  const float* ba  = (const float*)d_in[5];
  const float* Wb  = (const float*)d_in[6];
  const float* bb  = (const float*)d_in[7];
  const float* Wg  = (const float*)d_in[8];
  const float* Wo  = (const float*)d_in[9];
  const float* qcw = (const float*)d_in[10];
  const float* qcb = (const float*)d_in[11];
  const float* kcw = (const float*)d_in[12];
  const float* kcb = (const float*)d_in[13];
  const float* vcw = (const float*)d_in[14];
  const float* vcb = (const float*)d_in[15];
  const float* lnw = (const float*)d_in[16];
  const float* lnb = (const float*)d_in[17];
  (void)in_sizes; (void)n_in; (void)out_size;

  char* ws = (char*)d_ws;
  size_t off = 0;
  auto alloc = [&](size_t bytes) -> void* {
    void* p = ws + off; off += (bytes + 255) & ~(size_t)255; return p;
  };
  u16* WT    = (u16*)alloc((size_t)3 * HID_ * HID_ * 2);
  u16* WabT  = (u16*)alloc((size_t)32 * HID_ * 2);
  u16* xc    = (u16*)alloc((size_t)BT_ * HID_ * 2);
  u16* canon = (u16*)alloc((size_t)31008 * 2);
  u16* post  = (u16*)alloc((size_t)BT_ * QKVC * 2);
  float* abuf = (float*)alloc((size_t)2 * BT_ * 16 * 4);
  size_t base_off = off;

  size_t fused_need = base_off + (((size_t)BT_ * QKVC * 2 + 255) & ~(size_t)255);
  int fused = (fused_need <= ws_size);
  u16* preC;
  if (fused) preC = (u16*)alloc((size_t)BT_ * QKVC * 2);
  else       preC = (u16*)alloc((size_t)BT_ * HID_ * 2 * 2);
  if (off > ws_size) return;

  u16* cw_c  = canon;
  u16* cb_c  = canon + 24576;
  u16* ba_c  = canon + 30720;
  u16* bb_c  = canon + 30736;
  u16* lnw_c = canon + 30752;
  u16* lnb_c = canon + 30880;

  u16* o_raw = preC;
  u16* g_raw = post;
  u16* o_ln  = post + (size_t)BT_ * HID_;
  u16* WTg   = WT;

  dim3 tb(256), tb5(512);

  cvt_x_k<<<dim3(4096), tb, 0, stream>>>((const f32x4*)x, (u16x4*)xc, BT_ * HID_ / 4);
  cvt_small_k<<<dim3(122), tb, 0, stream>>>(qcw, kcw, vcw, qcb, kcb, vcb, ba, bb, lnw, lnb, canon);

  transpose_b<<<dim3(64, 64, 3), tb, 0, stream>>>(Wq, Wk, Wv, WT, HID_, HID_);
  transpose_b<<<dim3(1, 64, 2), tb, 0, stream>>>(Wa, Wb, Wb, WabT, HID_, 16);

  if (fused) {
    gemm256<<<dim3(QKVC / GBN, BT_ / GBM), tb5, 0, stream>>>(xc, HID_, WT, HID_, preC, QKVC, HID_, 0);
    conv_silu_k<<<dim3(BT_ * (QKVC / 8) / 256), tb, 0, stream>>>(preC, cw_c, cb_c, post);
  } else {
    for (int b = 0; b < B_; ++b) {
      const u16* xb = xc + (size_t)b * T_ * HID_;
      gemm256<<<dim3(QKVC / GBN, T_ / GBM), tb5, 0, stream>>>(xb, HID_, WT, HID_, preC, QKVC, HID_, 0);
      conv_silu_k<<<dim3(T_ * (QKVC / 8) / 256), tb, 0, stream>>>(
          preC, cw_c, cb_c, post + (size_t)b * T_ * QKVC);
    }
  }

  transpose_b<<<dim3(64, 64, 2), tb, 0, stream>>>(Wg, Wo, Wo, WTg, HID_, HID_);

  ab_k<<<dim3(BT_ / 8), tb, 0, stream>>>(xc, WabT, ba_c, bb_c, abuf);

  // chunked scan: 256 blocks x 512 threads (R14 pipelined 4-barrier schedule, best)
  chunk_scan_k<<<dim3(256), tb5, 0, stream>>>(post, abuf, o_raw);

  gemm256<<<dim3(HID_ / GBN, BT_ / GBM), tb5, 0, stream>>>(xc, HID_, WTg, HID_, g_raw, HID_, HID_, 0);

  ln_gate_k<<<dim3(BT_ * H_ / 4), tb, 0, stream>>>(o_raw, g_raw, lnw_c, lnb_c, o_ln);

  gemm256<<<dim3(HID_ / GBN, BT_ / GBM), tb5, 0, stream>>>(o_ln, HID_,
      WT + (size_t)HID_ * HID_, HID_, d_out, HID_, HID_, 1);
}

// Round 17
// 1194.554 us; speedup vs baseline: 1.0315x; 1.0152x over previous
//
#include <hip/hip_runtime.h>
#include <stdint.h>

#define H_   16
#define DK_  128
#define DV_  128
#define HID_ 2048
#define KS_  4
#define B_   4
#define T_   2048
#define BT_  (B_*T_)     // 8192
#define QKVC (3*HID_)    // 6144
#define C_   32          // scan chunk length
#define RS_  32          // state rows per block
#define NC_  (T_/C_)     // 64 chunks

typedef unsigned short u16;
typedef short  bf16x8 __attribute__((ext_vector_type(8)));
typedef u16    u16x8  __attribute__((ext_vector_type(8)));
typedef u16    u16x4  __attribute__((ext_vector_type(4)));
typedef float  f32x4  __attribute__((ext_vector_type(4)));

__device__ __forceinline__ float b2f(u16 u){
  union { unsigned int i; float f; } v; v.i = ((unsigned int)u) << 16; return v.f;
}
__device__ __forceinline__ u16 f2b(float f){
  unsigned int x = __float_as_uint(f);
  unsigned int r = (x + 0x7FFFu + ((x >> 16) & 1u)) >> 16;
  return (u16)r;
}
__device__ __forceinline__ float sigm(float x){ return 1.0f / (1.0f + __expf(-x)); }

#define MFMA16(a,b,c) __builtin_amdgcn_mfma_f32_16x16x32_bf16((a),(b),(c),0,0,0)

// ---------------- x conversion: f32 (bf16-valued) -> bf16, vectorized ----------------
__global__ __launch_bounds__(256) void cvt_x_k(const f32x4* __restrict__ src,
                                               u16x4* __restrict__ dst, int n4)
{
  int i0 = blockIdx.x * 256 + threadIdx.x;
  int stride = gridDim.x * 256;
  for (int i = i0; i < n4; i += stride) {
    f32x4 v = src[i];
    u16x4 r; r[0] = f2b(v[0]); r[1] = f2b(v[1]); r[2] = f2b(v[2]); r[3] = f2b(v[3]);
    dst[i] = r;
  }
}

// ---------------- small-tensor conversions ----------------
__global__ __launch_bounds__(256) void cvt_small_k(
    const float* __restrict__ qcw, const float* __restrict__ kcw, const float* __restrict__ vcw,
    const float* __restrict__ qcb, const float* __restrict__ kcb, const float* __restrict__ vcb,
    const float* __restrict__ ba,  const float* __restrict__ bb,
    const float* __restrict__ lnw, const float* __restrict__ lnb,
    u16* __restrict__ canon)
{
  int i = blockIdx.x * 256 + threadIdx.x;
  if (i >= 31008) return;
  float v;
  if (i < 24576) {
    const float* s = (i < 8192) ? qcw : (i < 16384) ? kcw : vcw;
    v = s[i & 8191];
  } else if (i < 30720) {
    int j = i - 24576;
    const float* s = (j < 2048) ? qcb : (j < 4096) ? kcb : vcb;
    v = s[j & 2047];
  } else if (i < 30752) {
    int j = i - 30720;
    v = (j < 16) ? ba[j] : bb[j - 16];
  } else {
    int j = i - 30752;
    v = (j < 128) ? lnw[j] : lnb[j - 128];
  }
  canon[i] = f2b(v);
}

// ---------------- batched transpose ----------------
__global__ __launch_bounds__(256) void transpose_b(const float* __restrict__ s0,
                                                   const float* __restrict__ s1,
                                                   const float* __restrict__ s2,
                                                   u16* __restrict__ dst,
                                                   int R, int C)
{
  int z = blockIdx.z;
  const float* src = (z == 0) ? s0 : (z == 1) ? s1 : s2;
  u16* d = dst + (size_t)z * R * C;
  __shared__ u16 t[32][33];
  int bx = blockIdx.x * 32;
  int by = blockIdx.y * 32;
  int lx = threadIdx.x & 31, ly = threadIdx.x >> 5;
  #pragma unroll
  for (int i = 0; i < 4; ++i) {
    int r = by + ly + i * 8, c = bx + lx;
    if (r < R && c < C) t[ly + i * 8][lx] = f2b(src[(size_t)r * C + c]);
  }
  __syncthreads();
  #pragma unroll
  for (int i = 0; i < 4; ++i) {
    int r = bx + ly + i * 8;
    int c = by + lx;
    if (r < C && c < R) d[(size_t)r * R + c] = t[lx][ly + i * 8];
  }
}

__device__ __forceinline__ void gload_lds16(const void* gp, void* lp){
  __builtin_amdgcn_global_load_lds(
      (const __attribute__((address_space(1))) void*)gp,
      (__attribute__((address_space(3))) void*)lp, 16, 0, 0);
}

// ---------------- 256x256 double-buffered bf16 GEMM (2-phase) ----------------
// Best measured GEMM for these shapes (non-scan 819 us). Counted-vmcnt variants
// (R11 BK=32: 859, R12 BK=64/BN=128: 905) both lost.
#define GBM 256
#define GBN 256
#define GBK 64

__global__ __launch_bounds__(512, 2) void gemm256(const u16* __restrict__ A, int lda,
                                                  const u16* __restrict__ Bt, int ldb,
                                                  void* __restrict__ C, int ldc,
                                                  int K, int out_f32)
{
  __shared__ u16 lsA[2][GBM * GBK];   // 64 KB
  __shared__ u16 lsB[2][GBN * GBK];   // 64 KB
  int tid = threadIdx.x, wid = tid >> 6, lane = tid & 63;
  int l16 = lane & 15, quad = lane >> 4;
  int wr = wid >> 2, wc = wid & 3;

  int nbx = gridDim.x;
  int nwg = nbx * gridDim.y;
  int flat = blockIdx.y * nbx + blockIdx.x;
  int swzid = ((nwg & 7) == 0) ? ((flat & 7) * (nwg >> 3) + (flat >> 3)) : flat;
  int m0 = (swzid / nbx) * GBM;
  int n0 = (swzid % nbx) * GBN;

  f32x4 acc[8][4] = {};

  auto STAGE = [&](int t, int bi){
    int k0 = t * GBK;
    #pragma unroll
    for (int ld = 0; ld < 4; ++ld) {
      int slot = ld * 512 + tid;
      int row = slot >> 3, cg = slot & 7;
      int lofs = (ld * 512 + wid * 64) * 8;          // wave-uniform base (elems)
      gload_lds16(A  + (size_t)(m0 + row) * lda + k0 + cg * 8, &lsA[bi][lofs]);
      gload_lds16(Bt + (size_t)(n0 + row) * ldb + k0 + cg * 8, &lsB[bi][lofs]);
    }
  };

  STAGE(0, 0);
  __syncthreads();

  int NT = K / GBK;
  for (int t = 0; t < NT; ++t) {
    int bi = t & 1;
    if (t + 1 < NT) STAGE(t + 1, bi ^ 1);
    const u16* pA = lsA[bi];
    const u16* pB = lsB[bi];
    #pragma unroll
    for (int ks = 0; ks < 2; ++ks) {
      bf16x8 bfr[4];
      #pragma unroll
      for (int ni = 0; ni < 4; ++ni)
        bfr[ni] = *(const bf16x8*)&pB[(wc * 64 + ni * 16 + l16) * GBK + ks * 32 + quad * 8];
      #pragma unroll
      for (int mi = 0; mi < 8; ++mi) {
        bf16x8 af = *(const bf16x8*)&pA[(wr * 128 + mi * 16 + l16) * GBK + ks * 32 + quad * 8];
        #pragma unroll
        for (int ni = 0; ni < 4; ++ni)
          acc[mi][ni] = MFMA16(af, bfr[ni], acc[mi][ni]);
      }
    }
    __syncthreads();
  }

  #pragma unroll
  for (int mi = 0; mi < 8; ++mi)
    #pragma unroll
    for (int ni = 0; ni < 4; ++ni)
      #pragma unroll
      for (int r = 0; r < 4; ++r) {
        int m = m0 + wr * 128 + mi * 16 + quad * 4 + r;
        int n = n0 + wc * 64 + ni * 16 + l16;
        if (out_f32) ((float*)C)[(size_t)m * ldc + n] = acc[mi][ni][r];
        else         ((u16*)C)[(size_t)m * ldc + n] = f2b(acc[mi][ni][r]);
      }
}

// ---------------- alpha/beta ----------------
__global__ __launch_bounds__(256) void ab_k(const u16* __restrict__ x,
                                            const u16* __restrict__ WabT,
                                            const u16* __restrict__ ba,
                                            const u16* __restrict__ bb,
                                            float* __restrict__ ab)
{
  int j = threadIdx.x & 31, rl = threadIdx.x >> 5;
  int row = blockIdx.x * 8 + rl;
  const u16x8* xr = (const u16x8*)(x + (size_t)row * HID_);
  const u16x8* wr = (const u16x8*)(WabT + (size_t)j * HID_);
  float acc = 0.f;
  for (int k = 0; k < HID_ / 8; ++k) {
    u16x8 xv = xr[k], wv = wr[k];
    #pragma unroll
    for (int i = 0; i < 8; ++i) acc += b2f(xv[i]) * b2f(wv[i]);
  }
  float bias = (j < 16) ? b2f(ba[j]) : b2f(bb[j - 16]);
  float sg = sigm(acc + bias);
  if (j < 16) ab[(size_t)row * 16 + j] = sg;
  else        ab[(size_t)BT_ * 16 + (size_t)row * 16 + (j - 16)] = sg;
}

// ---------------- causal dwconv (KS=4) + silu; ALL batches in one launch ----------------
__global__ __launch_bounds__(256) void conv_silu_k(const u16* __restrict__ in,   // [BT_][QKVC]
                                                   const u16* __restrict__ cwv,
                                                   const u16* __restrict__ cbv,
                                                   u16* __restrict__ out)
{
  int idx  = blockIdx.x * 256 + threadIdx.x;
  int col8 = idx % (QKVC / 8);
  int gt   = idx / (QKVC / 8);           // global row in [0, BT_)
  int t    = gt & (T_ - 1);              // within-batch time (causality boundary)
  int col  = col8 * 8;
  int s = col >> 11;

  u16 wl[32];
  #pragma unroll
  for (int i = 0; i < 4; ++i)
    *(u16x8*)(wl + i * 8) = *(const u16x8*)(cwv + (size_t)col * KS_ + i * 8);
  u16x8 bv = *(const u16x8*)(cbv + col);

  float acc[8];
  #pragma unroll
  for (int j = 0; j < 8; ++j) acc[j] = b2f(bv[j]);

  #pragma unroll
  for (int tap = 0; tap < KS_; ++tap) {
    int tt = t - 3 + tap;
    if (tt >= 0) {
      u16x8 xv = *(const u16x8*)(in + (size_t)(gt - 3 + tap) * QKVC + col);
      #pragma unroll
      for (int j = 0; j < 8; ++j) acc[j] = fmaf(b2f(xv[j]), b2f(wl[j * 4 + tap]), acc[j]);
    }
  }
  float scale = (s == 1) ? 0.08838834764831845f : 1.0f;
  u16x8 rv;
  #pragma unroll
  for (int j = 0; j < 8; ++j) {
    float a = acc[j];
    rv[j] = f2b(a * sigm(a) * scale);
  }
  *(u16x8*)(out + (size_t)gt * QKVC + col) = rv;
}

// ---------------- chunked gated delta-rule scan (UT transform, MFMA) ----------------
// R17 = R14 structure (383 us best) + solve dependency-chain fix:
//  * 4 independent accumulators in the triangular solve's dot (serial fmaf chain
//    ~t -> ~t/4 per step; the chain was ~2000 cy/chunk on the critical wave).
//  * SK0 column prefetched into registers before the loop (all solve inputs are
//    ready at loop entry; takes 32 b32 LDS loads off the dependency chain).
// Association order of the dot changes -> absmax may move a hair from 0.04443359
// (bf16-quantization dominated; every prior reorder left it bit-identical).
__global__ __launch_bounds__(512) void chunk_scan_k(const u16* __restrict__ qkv,
                                                    const float* __restrict__ ab,
                                                    u16* __restrict__ o)
{
  __shared__ __align__(16) char smem[107648];
  float (*SK0)[33] = (float(*)[33])(smem + 94464);
  float (*SQ0)[33] = (float(*)[33])(smem + 98688);
  float (*PL4)[4]  = (float(*)[4])(smem + 102912);
  float (*U)[33]   = (float(*)[33])(smem + 103424);
  u16 (*Sh)[136]   = (u16(*)[136])(smem + 34816);
  u16 (*Sl)[136]   = (u16(*)[136])(smem + 43520);

  int bid = blockIdx.x;
  int chain = bid & 63, rblk = bid >> 6;
  int b = chain >> 4, h = chain & 15;
  int tid = threadIdx.x, wv = tid >> 6, lane = tid & 63;
  int l16 = lane & 15, quad = lane >> 4;

  const u16* kbase = qkv + (size_t)b * T_ * QKVC + HID_ + h * DK_;
  const u16* qbase = qkv + (size_t)b * T_ * QKVC + h * DK_;
  const u16* vbase = qkv + (size_t)b * T_ * QKVC + 2 * HID_ + h * DV_ + rblk * RS_;
  const float* abase = ab + (size_t)b * T_ * 16 + h;
  const float* bbase = abase + (size_t)BT_ * 16;
  u16* obase = o + (size_t)b * T_ * 2048 + h * DV_ + rblk * RS_;

  f32x4 st[2];
  #pragma unroll
  for (int rt = 0; rt < 2; ++rt)
    #pragma unroll
    for (int r = 0; r < 4; ++r) st[rt][r] = 0.f;

  int jb = tid - 64;
  u16x8 stg[3];
  float avp = 0.f;

  auto LDA = [&](int c) {
    int t0 = c * C_;
    avp = (lane < 32) ? abase[(size_t)(t0 + lane) * 16]
                      : bbase[(size_t)(t0 + lane - 32) * 16];
  };
  auto LDI = [&](int c) {
    int t0 = c * C_;
    #pragma unroll
    for (int it = 0; it < 3; ++it) {
      int j = jb + it * 448;
      if (j < 512) {
        int t = j >> 4, g = j & 15;
        stg[it] = *(const u16x8*)(kbase + (size_t)(t0 + t) * QKVC + g * 8);
      } else if (j < 1024) {
        int j2 = j - 512, t = j2 >> 4, g = j2 & 15;
        stg[it] = *(const u16x8*)(qbase + (size_t)(t0 + t) * QKVC + g * 8);
      } else if (j < 1152) {
        int j2 = j - 1024, t = j2 >> 2, rg = j2 & 3;
        stg[it] = *(const u16x8*)(vbase + (size_t)(t0 + t) * QKVC + rg * 8);
      }
    }
  };
  auto WIM = [&](int p) {
    u16 (*Kim)[136] = (u16(*)[136])(smem + p * 8704);
    u16 (*Qim)[136] = (u16(*)[136])(smem + 17408 + p * 8704);
    u16 (*KT)[40]   = (u16(*)[40])(smem + 52224 + p * 10240);
    u16 (*Vim)[32]  = (u16(*)[32])(smem + 72704 + p * 2048);
    #pragma unroll
    for (int it = 0; it < 3; ++it) {
      int j = jb + it * 448;
      if (j < 512) {
        int t = j >> 4, g = j & 15;
        *(u16x8*)&Kim[t][g * 8] = stg[it];
        int blk = ((t >> 3) ^ (g & 3)) << 3;
        int tl = t & 7;
        #pragma unroll
        for (int e = 0; e < 8; ++e)
          KT[g * 8 + e][blk + tl] = stg[it][e];
      } else if (j < 1024) {
        int j2 = j - 512, t = j2 >> 4, g = j2 & 15;
        *(u16x8*)&Qim[t][g * 8] = stg[it];
      } else if (j < 1152) {
        int j2 = j - 1024, t = j2 >> 2, rg = j2 & 3;
        *(u16x8*)&Vim[t][rg * 8] = stg[it];
      }
    }
  };
  auto dotKK = [&](const u16 (*Kim)[136], float (*KK)[36], int mt, int nt) {
    f32x4 acc = {0.f,0.f,0.f,0.f};
    #pragma unroll
    for (int ks = 0; ks < 4; ++ks) {
      bf16x8 A = *(const bf16x8*)&Kim[mt * 16 + l16][ks * 32 + quad * 8];
      bf16x8 B = *(const bf16x8*)&Kim[nt * 16 + l16][ks * 32 + quad * 8];
      acc = MFMA16(A, B, acc);
    }
    #pragma unroll
    for (int r = 0; r < 4; ++r) KK[mt * 16 + quad * 4 + r][nt * 16 + l16] = acc[r];
  };
  auto dotKQ = [&](const u16 (*Qim)[136], const u16 (*Kim)[136], float (*KQ)[33],
                   int mt, int nt) {
    f32x4 acc = {0.f,0.f,0.f,0.f};
    #pragma unroll
    for (int ks = 0; ks < 4; ++ks) {
      bf16x8 A = *(const bf16x8*)&Qim[mt * 16 + l16][ks * 32 + quad * 8];
      bf16x8 B = *(const bf16x8*)&Kim[nt * 16 + l16][ks * 32 + quad * 8];
      acc = MFMA16(A, B, acc);
    }
    #pragma unroll
    for (int r = 0; r < 4; ++r) KQ[mt * 16 + quad * 4 + r][nt * 16 + l16] = acc[r];
  };
  auto dotS = [&](const u16 (*Aarr)[136], int tt, int rr, float (*OUT)[33]) {
    f32x4 acc = {0.f,0.f,0.f,0.f};
    #pragma unroll
    for (int ks = 0; ks < 4; ++ks) {
      bf16x8 A  = *(const bf16x8*)&Aarr[tt * 16 + l16][ks * 32 + quad * 8];
      bf16x8 Bh = *(const bf16x8*)&Sh[rr * 16 + l16][ks * 32 + quad * 8];
      bf16x8 Bl = *(const bf16x8*)&Sl[rr * 16 + l16][ks * 32 + quad * 8];
      acc = MFMA16(A, Bh, acc);
      acc = MFMA16(A, Bl, acc);
    }
    #pragma unroll
    for (int r = 0; r < 4; ++r) OUT[tt * 16 + quad * 4 + r][rr * 16 + l16] = acc[r];
  };

  // ---- prologue: stage chunk 0 images, preload chunk 1 regs, score chunk 0 ----
  if (wv == 0) LDA(0);
  else { LDI(0); WIM(0); LDI(1); }
  __syncthreads();
  {
    const u16 (*Kim0)[136] = (const u16(*)[136])(smem);
    const u16 (*Qim0)[136] = (const u16(*)[136])(smem + 17408);
    float (*KK0)[36] = (float(*)[36])(smem + 76800);
    float (*KQ0)[33] = (float(*)[33])(smem + 86016);
    if (wv >= 1 && wv <= 3) {
      const int mts[3] = {0, 1, 1}, nts[3] = {0, 0, 1};
      dotKK(Kim0, KK0, mts[wv - 1], nts[wv - 1]);
    } else if (wv >= 4 && wv <= 6) {
      const int mts[3] = {0, 1, 1}, nts[3] = {0, 0, 1};
      dotKQ(Qim0, Kim0, KQ0, mts[wv - 4], nts[wv - 4]);
    }
    // first reads of KK0/KQ0 are in iter0 ph3a, 2 barriers away
  }

  for (int c = 0; c < NC_; ++c) {
    int t0 = c * C_;
    int pc = c & 1, pn = pc ^ 1;
    const u16 (*KimC)[136] = (const u16(*)[136])(smem + pc * 8704);
    const u16 (*QimC)[136] = (const u16(*)[136])(smem + 17408 + pc * 8704);
    const u16 (*KTC)[40]   = (const u16(*)[40])(smem + 52224 + pc * 10240);
    const u16 (*VimC)[32]  = (const u16(*)[32])(smem + 72704 + pc * 2048);
    const float (*KKC)[36] = (const float(*)[36])(smem + 76800 + pc * 4608);
    const float (*KQC)[33] = (const float(*)[33])(smem + 86016 + pc * 4224);
    const u16 (*KimN)[136] = (const u16(*)[136])(smem + pn * 8704);
    const u16 (*QimN)[136] = (const u16(*)[136])(smem + 17408 + pn * 8704);
    float (*KKN)[36] = (float(*)[36])(smem + 76800 + pn * 4608);
    float (*KQN)[33] = (float(*)[33])(smem + 86016 + pn * 4224);

    // ---- ph1: state image; gates(c); write chunk c+1 images; issue LDI(c+2) ----
    #pragma unroll
    for (int rt = 0; rt < 2; ++rt)
      #pragma unroll
      for (int r = 0; r < 4; ++r) {
        float s = st[rt][r];
        u16 hi = f2b(s);
        float lo = s - b2f(hi);
        int row = rt * 16 + quad * 4 + r;
        int col = wv * 16 + l16;
        Sh[row][col] = hi;
        Sl[row][col] = f2b(lo);
      }

    if (wv == 0) {
      float av = avp;
      float p = av;
      #pragma unroll
      for (int d = 1; d < 32; d <<= 1) {
        float up = __shfl_up(p, d);
        if (lane >= d && lane < 32) p *= up;
      }
      float pm1 = __shfl_up(p, 1);
      float bt = __shfl(av, lane + 32);
      if (lane < 32) {
        if (lane == 0) pm1 = 1.f;
        f32x4 g;
        g[0] = bt * pm1; g[1] = bt; g[2] = 1.0f / p; g[3] = p;
        *(f32x4*)PL4[lane] = g;
      }
      if (c + 1 < NC_) LDA(c + 1);
    } else {
      if (c + 1 < NC_) WIM(pn);
      if (c + 2 < NC_) LDI(c + 2);
    }
    __syncthreads();

    // ---- ph2: state-dependent scores only (SK0/SQ0, 1 job per wave) ----
    if (wv < 4) dotS(KimC, wv >> 1, wv & 1, SK0);
    else        dotS(QimC, (wv - 4) >> 1, (wv - 4) & 1, SQ0);
    __syncthreads();

    // ---- ph3a: wave0 solve(c) || waves1-3 score chunk c+1 || waves4-7 G frags ----
    union { u16x8 u; bf16x8 b; } gh, gl;
    int omt = (wv - 4) >> 1, ont = (wv - 4) & 1;     // output tile for wv>=4
    if (wv == 0) {
      __builtin_amdgcn_s_setprio(1);                 // solve is the block critical path
      if (lane < 32) {
        float sk[C_];
        #pragma unroll
        for (int t = 0; t < C_; ++t) sk[t] = SK0[t][lane];   // off-chain prefetch
        float ub[C_];
        #pragma unroll
        for (int t = 0; t < C_; ++t) {
          f32x4 g = *(const f32x4*)PL4[t];
          float u = g[0] * sk[t] - g[1] * b2f(VimC[t][lane]);
          float a0 = 0.f, a1 = 0.f, a2 = 0.f, a3 = 0.f;      // 4-way chain split
          #pragma unroll
          for (int i4 = 0; i4 < t / 4; ++i4) {
            f32x4 kk = *(const f32x4*)&KKC[t][i4 * 4];       // uniform b128 broadcast
            a0 = fmaf(kk[0], ub[i4 * 4 + 0], a0);
            a1 = fmaf(kk[1], ub[i4 * 4 + 1], a1);
            a2 = fmaf(kk[2], ub[i4 * 4 + 2], a2);
            a3 = fmaf(kk[3], ub[i4 * 4 + 3], a3);
          }
          #pragma unroll
          for (int i = (t / 4) * 4; i < t; ++i)
            a0 = fmaf(KKC[t][i], ub[i], a0);
          float acc = (a0 + a1) + (a2 + a3);
          u = fmaf(-g[0], acc, u);
          U[t][lane] = u;
          ub[t] = g[2] * u;
        }
      }
      __builtin_amdgcn_s_setprio(0);
    } else if (wv <= 3) {
      if (c + 1 < NC_) {
        const int mts[3] = {0, 1, 1}, nts[3] = {0, 0, 1};
        dotKK(KimN, KKN, mts[wv - 1], nts[wv - 1]);
        dotKQ(QimN, KimN, KQN, mts[wv - 1], nts[wv - 1]);
      }
    } else {
      int trow = omt * 16 + l16;
      float Pt = PL4[trow][3];
      #pragma unroll
      for (int e = 0; e < 8; ++e) {
        int i = quad * 8 + e;
        float gv = (i <= trow) ? (-Pt * PL4[i][2] * KQC[trow][i]) : 0.f;
        u16 h2 = f2b(gv);
        gh.u[e] = h2; gl.u[e] = f2b(gv - b2f(h2));
      }
    }
    __syncthreads();

    // ---- ph3b: all waves state update from shared U; waves 4-7 outputs ----
    {
      float PL31 = PL4[31][3];

      #pragma unroll
      for (int rt = 0; rt < 2; ++rt) {
        union { u16x8 u; bf16x8 b; } ah, al;
        #pragma unroll
        for (int e = 0; e < 8; ++e) {
          int i = quad * 8 + e;
          float uv = U[i][rt * 16 + l16];
          float ucv = -PL31 * PL4[i][2] * uv;
          u16 hh = f2b(ucv);
          ah.u[e] = hh; al.u[e] = f2b(ucv - b2f(hh));
        }
        int col = wv * 16 + l16;
        bf16x8 Bk = *(const bf16x8*)&KTC[col][(quad ^ ((col >> 3) & 3)) << 3];
        f32x4 cacc;
        #pragma unroll
        for (int r = 0; r < 4; ++r) cacc[r] = PL31 * st[rt][r];
        cacc = MFMA16(ah.b, Bk, cacc);
        cacc = MFMA16(al.b, Bk, cacc);
        st[rt] = cacc;
      }

      if (wv >= 4) {
        union { u16x8 u; bf16x8 b; } uth, utl;
        #pragma unroll
        for (int e = 0; e < 8; ++e) {
          int i = quad * 8 + e;
          float uv = U[i][ont * 16 + l16];
          u16 h1 = f2b(uv);
          uth.u[e] = h1; utl.u[e] = f2b(uv - b2f(h1));
        }
        f32x4 oacc;
        #pragma unroll
        for (int r = 0; r < 4; ++r) {
          int t = omt * 16 + quad * 4 + r;
          oacc[r] = PL4[t][3] * SQ0[t][ont * 16 + l16];
        }
        oacc = MFMA16(gh.b, uth.b, oacc);
        oacc = MFMA16(gh.b, utl.b, oacc);
        oacc = MFMA16(gl.b, uth.b, oacc);
        #pragma unroll
        for (int r = 0; r < 4; ++r) {
          int t = omt * 16 + quad * 4 + r;
          obase[(size_t)(t0 + t) * 2048 + ont * 16 + l16] = f2b(oacc[r]);
        }
      }
    }
    __syncthreads();
  }
}

// ---------------- LayerNorm(DV) * sigmoid(g) ----------------
__global__ __launch_bounds__(256) void ln_gate_k(const u16* __restrict__ o_raw,
                                                 const u16* __restrict__ g,
                                                 const u16* __restrict__ lnw,
                                                 const u16* __restrict__ lnb,
                                                 u16* __restrict__ o_ln)
{
  int gid = blockIdx.x * 4 + (threadIdx.x >> 6);
  int lane = threadIdx.x & 63;
  int row = gid >> 4, h = gid & 15;
  size_t ofs = (size_t)row * 2048 + h * 128 + lane * 2;
  unsigned int e2 = *(const unsigned int*)(o_raw + ofs);
  float ex = b2f((u16)(e2 & 0xffff)), ey = b2f((u16)(e2 >> 16));
  float s = ex + ey, ss = ex * ex + ey * ey;
  #pragma unroll
  for (int m = 1; m < 64; m <<= 1) { s += __shfl_xor(s, m); ss += __shfl_xor(ss, m); }
  float mean = s * (1.f / 128.f);
  float var  = ss * (1.f / 128.f) - mean * mean;
  float rstd = rsqrtf(fmaxf(var, 0.f) + 1e-5f);
  float w0 = b2f(lnw[lane * 2]), w1 = b2f(lnw[lane * 2 + 1]);
  float b0 = b2f(lnb[lane * 2]), b1 = b2f(lnb[lane * 2 + 1]);
  unsigned int g2 = *(const unsigned int*)(g + ofs);
  float g0 = sigm(b2f((u16)(g2 & 0xffff))), g1 = sigm(b2f((u16)(g2 >> 16)));
  float r0 = ((ex - mean) * rstd * w0 + b0) * g0;
  float r1 = ((ey - mean) * rstd * w1 + b1) * g1;
  *(unsigned int*)(o_ln + ofs) = (unsigned int)f2b(r0) | ((unsigned int)f2b(r1) << 16);
}

// ---------------- host launch ----------------
extern "C" void kernel_launch(void* const* d_in, const int* in_sizes, int n_in,
                              void* d_out, int out_size, void* d_ws, size_t ws_size,
                              hipStream_t stream)
{
  const float* x   = (const float*)d_in[0];
  const float* Wq  = (const float*)d_in[1];
  const float* Wk  = (const float*)d_in[2];
  const float* Wv  = (const float*)d_in[3];
  const float* Wa  = (const float*)d_in[4];
  const float* ba  = (const float*)d_in[5];
  const float* Wb  = (const float*)d_in[6];
  const float* bb  = (const float*)d_in[7];
  const float* Wg  = (const float*)d_in[8];
  const float* Wo  = (const float*)d_in[9];
  const float* qcw = (const float*)d_in[10];
  const float* qcb = (const float*)d_in[11];
  const float* kcw = (const float*)d_in[12];
  const float* kcb = (const float*)d_in[13];
  const float* vcw = (const float*)d_in[14];
  const float* vcb = (const float*)d_in[15];
  const float* lnw = (const float*)d_in[16];
  const float* lnb = (const float*)d_in[17];
  (void)in_sizes; (void)n_in; (void)out_size;

  char* ws = (char*)d_ws;
  size_t off = 0;
  auto alloc = [&](size_t bytes) -> void* {
    void* p = ws + off; off += (bytes + 255) & ~(size_t)255; return p;
  };
  u16* WT    = (u16*)alloc((size_t)3 * HID_ * HID_ * 2);
  u16* WabT  = (u16*)alloc((size_t)32 * HID_ * 2);
  u16* xc    = (u16*)alloc((size_t)BT_ * HID_ * 2);
  u16* canon = (u16*)alloc((size_t)31008 * 2);
  u16* post  = (u16*)alloc((size_t)BT_ * QKVC * 2);
  float* abuf = (float*)alloc((size_t)2 * BT_ * 16 * 4);
  size_t base_off = off;

  size_t fused_need = base_off + (((size_t)BT_ * QKVC * 2 + 255) & ~(size_t)255);
  int fused = (fused_need <= ws_size);
  u16* preC;
  if (fused) preC = (u16*)alloc((size_t)BT_ * QKVC * 2);
  else       preC = (u16*)alloc((size_t)BT_ * HID_ * 2 * 2);
  if (off > ws_size) return;

  u16* cw_c  = canon;
  u16* cb_c  = canon + 24576;
  u16* ba_c  = canon + 30720;
  u16* bb_c  = canon + 30736;
  u16* lnw_c = canon + 30752;
  u16* lnb_c = canon + 30880;

  u16* o_raw = preC;
  u16* g_raw = post;
  u16* o_ln  = post + (size_t)BT_ * HID_;
  u16* WTg   = WT;

  dim3 tb(256), tb5(512);

  cvt_x_k<<<dim3(4096), tb, 0, stream>>>((const f32x4*)x, (u16x4*)xc, BT_ * HID_ / 4);
  cvt_small_k<<<dim3(122), tb, 0, stream>>>(qcw, kcw, vcw, qcb, kcb, vcb, ba, bb, lnw, lnb, canon);

  transpose_b<<<dim3(64, 64, 3), tb, 0, stream>>>(Wq, Wk, Wv, WT, HID_, HID_);
  transpose_b<<<dim3(1, 64, 2), tb, 0, stream>>>(Wa, Wb, Wb, WabT, HID_, 16);

  if (fused) {
    gemm256<<<dim3(QKVC / GBN, BT_ / GBM), tb5, 0, stream>>>(xc, HID_, WT, HID_, preC, QKVC, HID_, 0);
    conv_silu_k<<<dim3(BT_ * (QKVC / 8) / 256), tb, 0, stream>>>(preC, cw_c, cb_c, post);
  } else {
    for (int b = 0; b < B_; ++b) {
      const u16* xb = xc + (size_t)b * T_ * HID_;
      gemm256<<<dim3(QKVC / GBN, T_ / GBM), tb5, 0, stream>>>(xb, HID_, WT, HID_, preC, QKVC, HID_, 0);
      conv_silu_k<<<dim3(T_ * (QKVC / 8) / 256), tb, 0, stream>>>(
          preC, cw_c, cb_c, post + (size_t)b * T_ * QKVC);
    }
  }

  transpose_b<<<dim3(64, 64, 2), tb, 0, stream>>>(Wg, Wo, Wo, WTg, HID_, HID_);

  ab_k<<<dim3(BT_ / 8), tb, 0, stream>>>(xc, WabT, ba_c, bb_c, abuf);

  // chunked scan: 256 blocks x 512 threads (R14 schedule + solve chain split)
  chunk_scan_k<<<dim3(256), tb5, 0, stream>>>(post, abuf, o_raw);

  gemm256<<<dim3(HID_ / GBN, BT_ / GBM), tb5, 0, stream>>>(xc, HID_, WTg, HID_, g_raw, HID_, HID_, 0);

  ln_gate_k<<<dim3(BT_ * H_ / 4), tb, 0, stream>>>(o_raw, g_raw, lnw_c, lnb_c, o_ln);

  gemm256<<<dim3(HID_ / GBN, BT_ / GBM), tb5, 0, stream>>>(o_ln, HID_,
      WT + (size_t)HID_ * HID_, HID_, d_out, HID_, HID_, 1);
}